// Round 1
// baseline (348.958 us; speedup 1.0000x reference)
//
#include <hip/hip_runtime.h>

#define NPTS  1048576
#define GRID  512
#define NTILE 8192   // NPTS / 128

typedef __attribute__((ext_vector_type(8))) short  s16x8;
typedef __attribute__((ext_vector_type(4))) short  s16x4;
typedef __attribute__((ext_vector_type(4))) float  f32x4;

__device__ __forceinline__ unsigned short bf16r(float v) {
  unsigned u = __builtin_bit_cast(unsigned, v);
  return (unsigned short)((u + 0x7fffu + ((u >> 16) & 1u)) >> 16);
}
__device__ __forceinline__ float tanh_fast(float x) {
  float e = __builtin_amdgcn_exp2f(x * 2.8853900817779268f);   // exp(2x)
  return 1.0f - 2.0f * __builtin_amdgcn_rcpf(1.0f + e);
}
__device__ __forceinline__ float sigm_fast(float x) {
  return __builtin_amdgcn_rcpf(1.0f + __builtin_amdgcn_exp2f(x * -1.4426950408889634f));
}

// ws layout:
//   u16[0 .. 49152)  : W2,W3,W4 LDS images (16384 u16 each = 32KB).
//                      Image holds Wt[n][k'] bf16 where k' is the sigma-permuted
//                      k index (orig k = 16*(k'%8) + k'/8), at byte
//                      (n*256 + k'*2) ^ ((n&7)<<4)  (bank-conflict swizzle baked in).
//   float[@byte 98304]: W1p[2][128] sigma-permuted, then b1p[128] sigma-permuted.
__global__ void prep_kernel(const float* __restrict__ W1, const float* __restrict__ b1,
                            const float* __restrict__ W2, const float* __restrict__ W3,
                            const float* __restrict__ W4, unsigned short* __restrict__ ws)
{
  int tid = blockIdx.x * 256 + threadIdx.x;
  if (tid < 49152) {
    int m   = tid >> 14;        // which matrix
    int idx = tid & 16383;
    int n   = idx >> 7;         // output col
    int kp  = idx & 127;        // storage position k'
    int k   = ((kp & 7) << 4) + (kp >> 3);   // original k
    const float* W = (m == 0) ? W2 : (m == 1) ? W3 : W4;
    unsigned byte = (unsigned)(n * 256 + kp * 2) ^ (unsigned)((n & 7) << 4);
    ws[(m << 14) + (byte >> 1)] = bf16r(W[k * 128 + n]);
  } else if (tid < 49152 + 256) {
    int i = tid - 49152; int row = i >> 7; int p = i & 127;
    int j = ((p & 7) << 4) + (p >> 3);
    float* wsf = (float*)(ws + 49152);
    wsf[i] = W1[row * 128 + j];
  } else if (tid < 49152 + 384) {
    int p = tid - 49152 - 256;
    int j = ((p & 7) << 4) + (p >> 3);
    float* wsf = (float*)(ws + 49152);
    wsf[256 + p] = b1[j];
  }
}

__global__ __launch_bounds__(256, 2)
void mlp_kernel(const float* __restrict__ xy, const float* __restrict__ Uin,
                const float* __restrict__ b2, const float* __restrict__ b3,
                const float* __restrict__ b4, const float* __restrict__ W5,
                const float* __restrict__ b5, const unsigned short* __restrict__ ws,
                float* __restrict__ out)
{
  __shared__ __align__(16) unsigned char hbuf[32768];  // h tile: 128 rows x 128 k' bf16
  __shared__ __align__(16) unsigned char wbuf[32768];  // current layer Wt image

  const int tid  = threadIdx.x;
  const int lane = tid & 63;
  const int wid  = tid >> 6;   // 0..3
  const int wr   = wid >> 1;   // row half   (64 rows)
  const int wc   = wid & 1;    // col half   (64 cols)
  const int lg   = lane >> 4;  // lane group 0..3
  const int ln   = lane & 15;

  const float Uval = Uin[0];
  const float b5v  = (ln < 2) ? b5[ln] : 0.0f;

  // B-fragments for layer 5 (cols 0..1 live, 2..15 zero). k' = kt*32+lg*8+e -> orig k = 16e+4kt+lg
  s16x8 b5f[4];
#pragma unroll
  for (int kt = 0; kt < 4; ++kt) {
#pragma unroll
    for (int e = 0; e < 8; ++e) {
      float v = 0.0f;
      if (ln < 2) v = W5[(16 * e + 4 * kt + lg) * 2 + ln];
      b5f[kt][e] = (short)bf16r(v);
    }
  }

  // biases for layers 2..4, this wave's columns
  float biasr[3][4];
#pragma unroll
  for (int nt = 0; nt < 4; ++nt) {
    int j = wc * 64 + nt * 16 + ln;
    biasr[0][nt] = b2[j];
    biasr[1][nt] = b3[j];
    biasr[2][nt] = b4[j];
  }

  // layer-1 weights for this thread's sigma-block c0 (positions c0*8..c0*8+7)
  const float* W1p = (const float*)(ws + 49152);
  const float* b1p = W1p + 256;
  const int c0 = tid & 15;
  float w1x[8], w1y[8], b1r[8];
#pragma unroll
  for (int t = 0; t < 8; ++t) {
    w1x[t] = W1p[c0 * 8 + t];
    w1y[t] = W1p[128 + c0 * 8 + t];
    b1r[t] = b1p[c0 * 8 + t];
  }

  // stage W2 (image already swizzled -> linear copy)
#pragma unroll
  for (int i = 0; i < 8; ++i) {
    int off = i * 256 + tid;
    *(s16x8*)(wbuf + off * 16) = *(const s16x8*)(ws + off * 8);
  }

  for (int tile = blockIdx.x; tile < NTILE; tile += GRID) {
    const int pbase = tile << 7;

    // ---- layer 1: h1 = tanh(xy @ W1 + b1), straight to LDS (sigma layout) ----
#pragma unroll
    for (int i = 0; i < 8; ++i) {
      int p = i * 16 + (tid >> 4);
      float2 v = ((const float2*)xy)[pbase + p];
      s16x8 hv;
#pragma unroll
      for (int t = 0; t < 8; ++t) {
        float s = fmaf(v.x, w1x[t], fmaf(v.y, w1y[t], b1r[t]));
        hv[t] = (short)bf16r(tanh_fast(s));
      }
      unsigned byte = ((unsigned)(p * 256 + c0 * 16)) ^ ((unsigned)(p & 7) << 4);
      *(s16x8*)(hbuf + byte) = hv;
    }
    __syncthreads();   // h1 visible; W(layer2) visible

    // ---- layers 2..4 ----
#pragma unroll
    for (int l = 0; l < 3; ++l) {
      // A-fragments: this wave's 64 rows, all K
      s16x8 A[4][4];
#pragma unroll
      for (int mt = 0; mt < 4; ++mt)
#pragma unroll
        for (int kt = 0; kt < 4; ++kt) {
          int row = wr * 64 + mt * 16 + ln;
          unsigned byte = ((unsigned)(row * 256 + kt * 64 + lg * 16)) ^ ((unsigned)(row & 7) << 4);
          A[mt][kt] = *(const s16x8*)(hbuf + byte);
        }
      f32x4 acc[4][4];
#pragma unroll
      for (int mt = 0; mt < 4; ++mt)
#pragma unroll
        for (int nt = 0; nt < 4; ++nt)
          acc[mt][nt] = f32x4{0.f, 0.f, 0.f, 0.f};

#pragma unroll
      for (int nt = 0; nt < 4; ++nt) {
        s16x8 B[4];
#pragma unroll
        for (int kt = 0; kt < 4; ++kt) {
          int n = wc * 64 + nt * 16 + ln;
          unsigned byte = ((unsigned)(n * 256 + kt * 64 + lg * 16)) ^ ((unsigned)(n & 7) << 4);
          B[kt] = *(const s16x8*)(wbuf + byte);
        }
#pragma unroll
        for (int mt = 0; mt < 4; ++mt)
#pragma unroll
          for (int kt = 0; kt < 4; ++kt)
            acc[mt][nt] = __builtin_amdgcn_mfma_f32_16x16x32_bf16(A[mt][kt], B[kt], acc[mt][nt], 0, 0, 0);
      }
      __syncthreads();   // every wave done reading hbuf (A) and wbuf (B)

      // stage next W into wbuf: l=0 -> W3, l=1 -> W4, l=2 -> W2 (for next tile)
      const unsigned short* wsrc = ws + ((l < 2) ? (l + 1) * 16384 : 0);
#pragma unroll
      for (int i = 0; i < 8; ++i) {
        int off = i * 256 + tid;
        *(s16x8*)(wbuf + off * 16) = *(const s16x8*)(wsrc + off * 8);
      }

      // bias + tanh + writeback to hbuf. sigma layout makes the 4 nt values
      // of one (mt,reg) land contiguous -> single ds_write_b64.
#pragma unroll
      for (int mt = 0; mt < 4; ++mt) {
#pragma unroll
        for (int r = 0; r < 4; ++r) {
          s16x4 pk;
#pragma unroll
          for (int nt = 0; nt < 4; ++nt)
            pk[nt] = (short)bf16r(tanh_fast(acc[mt][nt][r] + biasr[l][nt]));
          int row = wr * 64 + mt * 16 + lg * 4 + r;
          unsigned byte = ((unsigned)(row * 256 + ln * 16 + wc * 8)) ^ ((unsigned)(row & 7) << 4);
          *(s16x4*)(hbuf + byte) = pk;
        }
      }
      __syncthreads();
    }

    // ---- layer 5 + epilogue (each wave: 32 rows) ----
    f32x4 acc5[2];
#pragma unroll
    for (int mt = 0; mt < 2; ++mt) acc5[mt] = f32x4{0.f, 0.f, 0.f, 0.f};
#pragma unroll
    for (int mt = 0; mt < 2; ++mt)
#pragma unroll
      for (int kt = 0; kt < 4; ++kt) {
        int row = wid * 32 + mt * 16 + ln;
        unsigned byte = ((unsigned)(row * 256 + kt * 64 + lg * 16)) ^ ((unsigned)(row & 7) << 4);
        s16x8 a = *(const s16x8*)(hbuf + byte);
        acc5[mt] = __builtin_amdgcn_mfma_f32_16x16x32_bf16(a, b5f[kt], acc5[mt], 0, 0, 0);
      }
    if (ln < 2) {
#pragma unroll
      for (int mt = 0; mt < 2; ++mt)
#pragma unroll
        for (int r = 0; r < 4; ++r) {
          int p = pbase + wid * 32 + mt * 16 + lg * 4 + r;
          float uh = acc5[mt][r] + b5v;
          float2 v = ((const float2*)xy)[p];
          float Bm = v.x * (1.0f - v.x) * v.y * (1.0f - v.y);
          if (ln == 0) {
            float psi = sigm_fast(50.0f * (v.x - 0.05f)) * sigm_fast(50.0f * (0.95f - v.x));
            out[p] = Uval * v.y * psi + Bm * uh;
          } else {
            out[NPTS + p] = Bm * uh;
          }
        }
    }
    __syncthreads();   // protect hbuf before next tile's layer-1 writes
  }
}

extern "C" void kernel_launch(void* const* d_in, const int* in_sizes, int n_in,
                              void* d_out, int out_size, void* d_ws, size_t ws_size,
                              hipStream_t stream) {
  const float* xy = (const float*)d_in[0];
  const float* U  = (const float*)d_in[1];
  const float* W1 = (const float*)d_in[2];
  const float* b1 = (const float*)d_in[3];
  const float* W2 = (const float*)d_in[4];
  const float* b2 = (const float*)d_in[5];
  const float* W3 = (const float*)d_in[6];
  const float* b3 = (const float*)d_in[7];
  const float* W4 = (const float*)d_in[8];
  const float* b4 = (const float*)d_in[9];
  const float* W5 = (const float*)d_in[10];
  const float* b5 = (const float*)d_in[11];
  unsigned short* ws = (unsigned short*)d_ws;   // needs ~100 KB
  float* out = (float*)d_out;

  prep_kernel<<<194, 256, 0, stream>>>(W1, b1, W2, W3, W4, ws);
  mlp_kernel<<<GRID, 256, 0, stream>>>(xy, U, b2, b3, b4, W5, b5, ws, out);
}